// Round 1
// baseline (284.079 us; speedup 1.0000x reference)
//
#include <hip/hip_runtime.h>

#define GEPS 1e-10f

// ---------------------------------------------------------------------------
// Kernel 1: pooled[row] = mean(relu(x[row, 0:196]))  for row in [0, B*C_in)
// One wave (64 lanes) per row. 196 floats = 49 float4 -> lanes 0..48 each
// load one float4 (784 B contiguous, coalesced), relu+sum, shuffle-reduce.
// ---------------------------------------------------------------------------
__global__ __launch_bounds__(256) void pool_kernel(const float* __restrict__ x,
                                                   float* __restrict__ pooled,
                                                   int nrows) {
    int wave = (blockIdx.x * blockDim.x + threadIdx.x) >> 6;
    int lane = threadIdx.x & 63;
    if (wave >= nrows) return;
    const float4* row = (const float4*)(x + (size_t)wave * 196);  // 784B aligned
    float s = 0.0f;
    if (lane < 49) {
        float4 v = row[lane];
        s = fmaxf(v.x, 0.0f) + fmaxf(v.y, 0.0f) + fmaxf(v.z, 0.0f) + fmaxf(v.w, 0.0f);
    }
    #pragma unroll
    for (int off = 32; off; off >>= 1) s += __shfl_down(s, off, 64);
    if (lane == 0) pooled[wave] = s * (1.0f / 196.0f);
}

// ---------------------------------------------------------------------------
// Kernel 2: per batch row b (one block of 256 threads):
//   logits[a] = dot(pooled[b,:], w[a,:])        (a = t&31, seg = t>>5, 128/seg)
//   score[a]  = logits[a] + gumbel(u[b,a])      (argmax-invariant reduction of
//                                                the softmax/temperature chain)
//   amax      = argmax_a score[a]  (first-max tie-break, matches jnp.argmax)
//   out[b]             = (float)amax
//   out[256 + b*1024:] = channel_gates[amax, :]
// ---------------------------------------------------------------------------
__global__ __launch_bounds__(256) void head_kernel(const float* __restrict__ pooled,
                                                   const float* __restrict__ gumbel_u,
                                                   const float* __restrict__ w,
                                                   const float* __restrict__ gates,
                                                   float* __restrict__ out) {
    const int b = blockIdx.x;
    const int t = threadIdx.x;
    __shared__ float sp[1024];       // pooled row
    __shared__ float partial[256];   // per-(a,seg) dot partials
    __shared__ float score[32];
    __shared__ int s_amax;

    // Stage pooled[b, :] into LDS (coalesced float4).
    ((float4*)sp)[t] = ((const float4*)(pooled + (size_t)b * 1024))[t];
    __syncthreads();

    const int a   = t & 31;
    const int seg = t >> 5;  // 0..7, each covers 128 channels
    const float4* wr4 = (const float4*)(w + (size_t)a * 1024 + seg * 128);
    const float4* pp4 = (const float4*)(sp + seg * 128);
    float acc = 0.0f;
    #pragma unroll
    for (int i = 0; i < 32; ++i) {
        float4 wv = wr4[i];
        float4 pv = pp4[i];
        acc += wv.x * pv.x + wv.y * pv.y + wv.z * pv.z + wv.w * pv.w;
    }
    partial[t] = acc;
    __syncthreads();

    if (t < 32) {
        float logit = 0.0f;
        #pragma unroll
        for (int s = 0; s < 8; ++s) logit += partial[s * 32 + t];
        float u = gumbel_u[b * 32 + t];
        float g = -logf(-logf(u + GEPS) + GEPS);
        score[t] = logit + g;
    }
    __syncthreads();

    if (t == 0) {
        int amax = 0;
        float best = score[0];
        #pragma unroll
        for (int i = 1; i < 32; ++i) {
            if (score[i] > best) { best = score[i]; amax = i; }  // strict > => first max
        }
        s_amax = amax;
        out[b] = (float)amax;  // sampled_actions as float32
    }
    __syncthreads();

    const int amax = s_amax;
    float4 gv = ((const float4*)(gates + (size_t)amax * 1024))[t];
    ((float4*)(out + 256 + (size_t)b * 1024))[t] = gv;
}

extern "C" void kernel_launch(void* const* d_in, const int* in_sizes, int n_in,
                              void* d_out, int out_size, void* d_ws, size_t ws_size,
                              hipStream_t stream) {
    const float* x        = (const float*)d_in[0];  // [256,1024,14,14]
    const float* gumbel_u = (const float*)d_in[1];  // [256,32]
    const float* fc1_w    = (const float*)d_in[2];  // [32,1024]
    const float* gates    = (const float*)d_in[3];  // [32,1024]
    float* out    = (float*)d_out;                  // [256 + 256*1024]
    float* pooled = (float*)d_ws;                   // [256*1024] = 1 MB scratch

    const int nrows = 256 * 1024;       // B * C_in
    const int blocks = nrows / 4;       // 4 waves (rows) per 256-thread block
    pool_kernel<<<blocks, 256, 0, stream>>>(x, pooled, nrows);
    head_kernel<<<256, 256, 0, stream>>>(pooled, gumbel_u, fc1_w, gates, out);
}